// Round 2
// baseline (760.691 us; speedup 1.0000x reference)
//
#include <hip/hip_runtime.h>

// Problem constants (from the reference setup):
//   B = 2, T = 1'000'000, C = 16, G = 500'000, K = 9
// out[b, g, k, c] = textures[b, group_idx[g, k], c]
// C = 16 floats = 4 float4 per texel row.

typedef float f4 __attribute__((ext_vector_type(4)));  // clang vector, OK for nontemporal builtins

constexpr long long T_ = 1000000;
constexpr int       C4 = 4;                // float4 chunks per texel row
constexpr long long GK = 500000LL * 9;     // flattened group*K count

__global__ __launch_bounds__(256) void
TMSCNNTexturesToFlattenedGroups_74294344286542_kernel(
    const f4* __restrict__ textures,   // [B * T * C4] in float4 units
    const int* __restrict__ group_idx, // [G * K]
    f4*       __restrict__ out)        // [B * GK * C4] in float4 units
{
    unsigned int tid = blockIdx.x * blockDim.x + threadIdx.x;
    const unsigned long long total = (unsigned long long)GK * C4;
    if (tid >= total) return;

    const int          c4 = tid & 3;       // which float4 of the 64B texel row
    const unsigned int gk = tid >> 2;      // flattened (g, k)

    const int idx = group_idx[gk];

    // Source offsets (float4 units) for b=0 and b=1
    const long long src0 = (long long)idx * C4 + c4;
    const long long src1 = (T_ + (long long)idx) * C4 + c4;

    const f4 v0 = textures[src0];
    const f4 v1 = textures[src1];

    // Destination offsets (float4 units)
    const long long dst0 = (long long)gk * C4 + c4;
    const long long dst1 = (GK + (long long)gk) * C4 + c4;

    // Streaming writes: skip L2 pollution, keep cache capacity for gathers.
    __builtin_nontemporal_store(v0, &out[dst0]);
    __builtin_nontemporal_store(v1, &out[dst1]);
}

extern "C" void kernel_launch(void* const* d_in, const int* in_sizes, int n_in,
                              void* d_out, int out_size, void* d_ws, size_t ws_size,
                              hipStream_t stream) {
    // d_in[0] = mesh_ids  (int32, unused by the reference)
    // d_in[1] = textures  (float32, [B, T, C])
    // d_in[2] = group_idx (int32,   [G, K])
    const f4*  textures  = (const f4*)d_in[1];
    const int* group_idx = (const int*)d_in[2];
    f4*        out       = (f4*)d_out;

    const unsigned long long total = (unsigned long long)GK * C4; // 18M threads
    const int threads = 256;
    const int blocks  = (int)((total + threads - 1) / threads);

    TMSCNNTexturesToFlattenedGroups_74294344286542_kernel<<<blocks, threads, 0, stream>>>(
        textures, group_idx, out);
}